// Round 2
// baseline (12298.573 us; speedup 1.0000x reference)
//
#include <hip/hip_runtime.h>
#include <stdint.h>

#define SEQ  2048
#define HID  2048
#define INP  1024
#define OUTW 512
#define SENT 0x7F7F7F7Fu        // fp32 sentinel (fallback path)
#define SENTH 0x7F7Fu           // bf16 sentinel halfword; |h|<1 so never a real h

__device__ __forceinline__ unsigned short f2bf(float x){
  unsigned int u = __float_as_uint(x);
  u += 0x7fffu + ((u >> 16) & 1u);           // RNE
  return (unsigned short)(u >> 16);
}
__device__ __forceinline__ float bf_lo(unsigned int w){ return __uint_as_float(w << 16); }
__device__ __forceinline__ float bf_hi(unsigned int w){ return __uint_as_float(w & 0xffff0000u); }
// any 16-bit halfword of x equal to SENTH?  (exact existence test)
__device__ __forceinline__ bool has_sent(unsigned long long x){
  unsigned long long y = x ^ 0x7F7F7F7F7F7F7F7FULL;
  return ((y - 0x0001000100010001ULL) & ~y & 0x8000800080008000ULL) != 0ULL;
}

// ---------------- Phase 0: sentinel fill (generic) ----------------
__global__ __launch_bounds__(256)
void fill_sent(uint4* __restrict__ p){
  size_t i = (size_t)blockIdx.x*blockDim.x + threadIdx.x;
  p[i] = make_uint4(SENT,SENT,SENT,SENT);
}

// ---------------- Phase A: Xproj[b][t][u][g] = W_g[j][2048:] @ x_t + b_g[j], bf16 ----------------
__global__ __launch_bounds__(256)
void xproj_gemm(const float* __restrict__ Wf, const float* __restrict__ Wi,
                const float* __restrict__ Wc, const float* __restrict__ Wo,
                const float* __restrict__ bfv, const float* __restrict__ biv,
                const float* __restrict__ bcv, const float* __restrict__ bov,
                const float* __restrict__ X, unsigned short* __restrict__ xproj)
{
  __shared__ float As[16][68];
  __shared__ float Bs[16][68];
  const int t0 = blockIdx.x * 64;
  const int r0 = blockIdx.y * 64;
  const int gate = r0 >> 11;
  const int j0 = r0 & 2047;
  const float* Wg = gate==0?Wf:gate==1?Wi:gate==2?Wc:Wo;
  const float* bg = gate==0?bfv:gate==1?biv:gate==2?bcv:bov;
  const int tid = threadIdx.x;
  const int tx = tid & 15, ty = tid >> 4;
  const int lr = tid >> 2;
  const int lk = (tid & 3) * 4;
  float acc[4][4] = {};
  for (int k0 = 0; k0 < INP; k0 += 16){
    float4 av = *(const float4*)(Wg + (size_t)(j0+lr)*3072 + 2048 + k0 + lk);
    float4 bv = *(const float4*)(X  + (size_t)(t0+lr)*INP  + k0 + lk);
    __syncthreads();
    As[lk+0][lr]=av.x; As[lk+1][lr]=av.y; As[lk+2][lr]=av.z; As[lk+3][lr]=av.w;
    Bs[lk+0][lr]=bv.x; Bs[lk+1][lr]=bv.y; Bs[lk+2][lr]=bv.z; Bs[lk+3][lr]=bv.w;
    __syncthreads();
    #pragma unroll
    for (int kk=0;kk<16;kk++){
      float a[4], bb[4];
      #pragma unroll
      for (int i=0;i<4;i++) a[i]  = As[kk][ty*4+i];
      #pragma unroll
      for (int j=0;j<4;j++) bb[j] = Bs[kk][tx*4+j];
      #pragma unroll
      for (int i=0;i<4;i++)
        #pragma unroll
        for (int j=0;j<4;j++)
          acc[i][j] = fmaf(a[i], bb[j], acc[i][j]);
    }
  }
  #pragma unroll
  for (int i=0;i<4;i++){
    int j = j0 + ty*4 + i;
    float bias = bg[j];
    int bb = j >> 3, u = j & 7;
    #pragma unroll
    for (int jj=0;jj<4;jj++){
      int t = t0 + tx*4 + jj;
      size_t idx = (((size_t)bb*SEQ + t)*8 + u)*4 + gate;   // [b][t][u][g]
      xproj[idx] = f2bf(acc[i][jj] + bias);
    }
  }
}

// ---------------- Phase B (primary): bf16 exchange, solo-poller scan ----------------
// 256 blocks x 512 thr (8 waves). Wave w owns hidden unit u = 8b+w, all 4 gate
// rows (4x2048 fp32) register-resident.
// Wave 0 = sole fabric poller: loads the whole 4KB bf16 row h_{t-1} (64B/lane,
// layout == its own operand layout), sentinel-detects, stages it to LDS,
// release-flags `done`, then computes its unit DIRECTLY from the polled regs.
// Waves 1-7: acquire-spin on `done` (LDS, cheap), ds_read operands, compute,
// publish. No __syncthreads in the loop, no redundant fabric polling.
// LDS double-buffer safety (causal): wave0 stages row t-1 into buf (t-1)&1 at
// step t only after detecting row t-1 complete, which requires THIS block's
// waves to have published h_{t-1}, which orders after their step-(t-1) reads of
// buf (t-1)&1's previous contents. Guards bound all spins (fail wrong, no hang).
__global__ __launch_bounds__(512, 2)
void lstm_scan(const float* __restrict__ Wf, const float* __restrict__ Wi,
               const float* __restrict__ Wc, const float* __restrict__ Wo,
               const unsigned short* __restrict__ xproj,
               unsigned short* __restrict__ hx,   // bf16 exchange [SEQ][HID] (ws)
               float* __restrict__ hist)          // fp32 output hidden [SEQ][HID]
{
  const int b    = blockIdx.x;
  const int tid  = threadIdx.x;
  const int wv   = tid >> 6;
  const int lane = tid & 63;
  const int u    = b*8 + wv;

  __shared__ unsigned int h_lds[2][HID/2];   // bf16 rows, 4KB each
  __shared__ int done;                       // last staged row index

  if (tid == 0) done = -1;
  __syncthreads();

  // fp32 weights: wreg[r][kc*8+j] = W_{gate r}[u][8*lane + 512*kc + j]
  const float* const Wm[4] = {Wf, Wi, Wc, Wo};
  float wreg[4][32];
  #pragma unroll
  for (int r=0;r<4;r++){
    const float* rowp = Wm[r] + (size_t)u*3072;
    #pragma unroll
    for (int kc=0;kc<4;kc++){
      float4 f0 = *(const float4*)(rowp + 8*lane + 512*kc);
      float4 f1 = *(const float4*)(rowp + 8*lane + 512*kc + 4);
      wreg[r][kc*8+0]=f0.x; wreg[r][kc*8+1]=f0.y; wreg[r][kc*8+2]=f0.z; wreg[r][kc*8+3]=f0.w;
      wreg[r][kc*8+4]=f1.x; wreg[r][kc*8+5]=f1.y; wreg[r][kc*8+6]=f1.z; wreg[r][kc*8+7]=f1.w;
    }
  }

  float c = 0.0f;
  const unsigned short* xpp = xproj + (size_t)b*SEQ*32 + wv*4 + lane; // lane<4 valid

  for (int t=0; t<SEQ; t++){
    float xp = (lane < 4) ? bf_lo((unsigned)xpp[(size_t)t*32]) : 0.0f;

    uint4 hw0, hw1, hw2, hw3;     // this lane's operands: cols 8*lane+512*kc..+7 (bf16)
    if (t == 0){
      hw0 = hw1 = hw2 = hw3 = make_uint4(0u,0u,0u,0u);
    } else if (wv == 0){
      // ---- sole poller: full row, 8 qwords/lane ----
      const char* hb = (const char*)(hx + (size_t)(t-1)*HID);
      unsigned long long q[8];
      #pragma unroll
      for (int kc=0;kc<4;kc++){
        const unsigned long long* p = (const unsigned long long*)(hb + 1024*kc + 16*lane);
        q[2*kc]   = __hip_atomic_load(p,   __ATOMIC_RELAXED, __HIP_MEMORY_SCOPE_AGENT);
        q[2*kc+1] = __hip_atomic_load(p+1, __ATOMIC_RELAXED, __HIP_MEMORY_SCOPE_AGENT);
      }
      int gd = 0;
      for(;;){
        bool bb[8]; bool any = false;
        #pragma unroll
        for (int i=0;i<8;i++){ bb[i] = has_sent(q[i]); any |= bb[i]; }
        if (!any || gd >= (1<<17)) break;     // guard: fail wrong, never hang
        #pragma unroll
        for (int i=0;i<8;i++) if (bb[i]){
          const unsigned long long* p =
            (const unsigned long long*)(hb + 1024*(i>>1) + 16*lane + 8*(i&1));
          q[i] = __hip_atomic_load(p, __ATOMIC_RELAXED, __HIP_MEMORY_SCOPE_AGENT);
        }
        gd++;
      }
      // stage to LDS + keep as own operands (poll layout == operand layout)
      char* db = (char*)&h_lds[(t-1)&1][0];
      uint4 v0, v1, v2, v3;
      v0.x=(unsigned)q[0]; v0.y=(unsigned)(q[0]>>32); v0.z=(unsigned)q[1]; v0.w=(unsigned)(q[1]>>32);
      v1.x=(unsigned)q[2]; v1.y=(unsigned)(q[2]>>32); v1.z=(unsigned)q[3]; v1.w=(unsigned)(q[3]>>32);
      v2.x=(unsigned)q[4]; v2.y=(unsigned)(q[4]>>32); v2.z=(unsigned)q[5]; v2.w=(unsigned)(q[5]>>32);
      v3.x=(unsigned)q[6]; v3.y=(unsigned)(q[6]>>32); v3.z=(unsigned)q[7]; v3.w=(unsigned)(q[7]>>32);
      *(uint4*)(db +    0 + 16*lane) = v0;
      *(uint4*)(db + 1024 + 16*lane) = v1;
      *(uint4*)(db + 2048 + 16*lane) = v2;
      *(uint4*)(db + 3072 + 16*lane) = v3;
      hw0 = v0; hw1 = v1; hw2 = v2; hw3 = v3;
      if (lane == 0)
        __hip_atomic_store(&done, t-1, __ATOMIC_RELEASE, __HIP_MEMORY_SCOPE_WORKGROUP);
    } else {
      // ---- consumer waves: cheap LDS flag spin, then ds_read ----
      int g = 0;
      while (__hip_atomic_load(&done, __ATOMIC_ACQUIRE, __HIP_MEMORY_SCOPE_WORKGROUP) < t-1
             && g < (1<<20)) g++;
      const char* rb = (const char*)&h_lds[(t-1)&1][0];
      hw0 = *(const uint4*)(rb +    0 + 16*lane);
      hw1 = *(const uint4*)(rb + 1024 + 16*lane);
      hw2 = *(const uint4*)(rb + 2048 + 16*lane);
      hw3 = *(const uint4*)(rb + 3072 + 16*lane);
    }

    // ---- dot: 4 gate rows x 32 cols/lane, 2 partial accs/gate (short dep chain) ----
    float p0[4] = {0.f,0.f,0.f,0.f};
    float p1[4] = {0.f,0.f,0.f,0.f};
    const uint4 hws[4] = {hw0, hw1, hw2, hw3};
    #pragma unroll
    for (int kc=0;kc<4;kc++){
      uint4 hw = hws[kc];
      float hf[8];
      hf[0]=bf_lo(hw.x); hf[1]=bf_hi(hw.x); hf[2]=bf_lo(hw.y); hf[3]=bf_hi(hw.y);
      hf[4]=bf_lo(hw.z); hf[5]=bf_hi(hw.z); hf[6]=bf_lo(hw.w); hf[7]=bf_hi(hw.w);
      #pragma unroll
      for (int r=0;r<4;r++){
        #pragma unroll
        for (int j=0;j<4;j++) p0[r] = fmaf(wreg[r][kc*8+j],   hf[j],   p0[r]);
        #pragma unroll
        for (int j=0;j<4;j++) p1[r] = fmaf(wreg[r][kc*8+4+j], hf[4+j], p1[r]);
      }
    }
    float acc[4];
    #pragma unroll
    for (int r=0;r<4;r++) acc[r] = p0[r] + p1[r];

    // ---- pair-folding butterfly: lane l ends with gate (l&3) fully reduced ----
    const int b0 = lane & 1;
    const int b1 = lane & 2;
    float x01 = b0 ? acc[1] : acc[0];
    float y01 = b0 ? acc[0] : acc[1];
    x01 += __shfl_xor(y01, 1);
    float x23 = b0 ? acc[3] : acc[2];
    float y23 = b0 ? acc[2] : acc[3];
    x23 += __shfl_xor(y23, 1);
    float xk = b1 ? x23 : x01;
    float yk = b1 ? x01 : x23;
    xk += __shfl_xor(yk, 2);
    xk += __shfl_xor(xk, 4);
    xk += __shfl_xor(xk, 8);
    xk += __shfl_xor(xk, 16);
    xk += __shfl_xor(xk, 32);

    // ---- activations in-wave ----
    float pre = xk + __shfl(xp, lane & 3);
    const bool ist = ((lane & 3) == 2);
    float px = ist ? fminf(15.0f, fmaxf(-15.0f, pre)) : pre;
    float e  = __expf(ist ? -2.0f*px : -px);
    float d  = 1.0f/(1.0f + e);
    float gv = ist ? (1.0f - e)*d : d;

    float f  = __shfl(gv, 0);
    float ii = __shfl(gv, 1);
    float cg = __shfl(gv, 2);
    float o  = __shfl(gv, 3);

    c = fmaf(f, c, ii*cg);
    float cx = fminf(15.0f, fmaxf(-15.0f, c));
    float e2 = __expf(-2.0f*cx);
    float h  = o * (1.0f - e2)/(1.0f + e2);

    // ---- publish: bf16 signal first (lowest latency), fp32 output second ----
    if (lane == 0){
      __hip_atomic_store(hx + (size_t)t*HID + u, f2bf(h),
                         __ATOMIC_RELAXED, __HIP_MEMORY_SCOPE_AGENT);
      hist[(size_t)t*HID + u] = h;
    }
  }
}

// ---------------- Phase B (fallback, ws too small): round-1 fp32 scan ----------------
__global__ __launch_bounds__(512, 2)
void lstm_persistent_fb(const float* __restrict__ Wf, const float* __restrict__ Wi,
                        const float* __restrict__ Wc, const float* __restrict__ Wo,
                        const unsigned short* __restrict__ xproj,
                        float* __restrict__ hist)
{
  const int b    = blockIdx.x;
  const int tid  = threadIdx.x;
  const int wv   = tid >> 6;
  const int lane = tid & 63;
  const int u    = b*8 + wv;

  __shared__ unsigned int h_lds[2][HID/2];

  const float* const Wm[4] = {Wf, Wi, Wc, Wo};
  float wreg[4][32];
  #pragma unroll
  for (int r=0;r<4;r++){
    const float* rowp = Wm[r] + (size_t)u*3072;
    #pragma unroll
    for (int kc=0;kc<4;kc++){
      float4 f0 = *(const float4*)(rowp + 8*lane + 512*kc);
      float4 f1 = *(const float4*)(rowp + 8*lane + 512*kc + 4);
      wreg[r][kc*8+0]=f0.x; wreg[r][kc*8+1]=f0.y; wreg[r][kc*8+2]=f0.z; wreg[r][kc*8+3]=f0.w;
      wreg[r][kc*8+4]=f1.x; wreg[r][kc*8+5]=f1.y; wreg[r][kc*8+6]=f1.z; wreg[r][kc*8+7]=f1.w;
    }
  }

  float c = 0.0f;
  const unsigned short* xpp = xproj + (size_t)b*SEQ*32 + wv*4 + lane;

  for (int t=0; t<SEQ; t++){
    float xp = (lane < 4) ? bf_lo((unsigned)xpp[(size_t)t*32]) : 0.0f;

    uint2 pk;
    if (t == 0){
      pk.x = 0u; pk.y = 0u;
    } else {
      const unsigned long long* hp =
        (const unsigned long long*)(hist + (size_t)(t-1)*HID) + 2*tid;
      unsigned long long qa = __hip_atomic_load(hp,   __ATOMIC_RELAXED, __HIP_MEMORY_SCOPE_AGENT);
      unsigned long long qb = __hip_atomic_load(hp+1, __ATOMIC_RELAXED, __HIP_MEMORY_SCOPE_AGENT);
      int gd = 0;
      for(;;){
        bool ba = ((unsigned)qa==SENT) | ((unsigned)(qa>>32)==SENT);
        bool bb = ((unsigned)qb==SENT) | ((unsigned)(qb>>32)==SENT);
        if (!(ba|bb) || gd >= (1<<17)) break;
        if (ba) qa = __hip_atomic_load(hp,   __ATOMIC_RELAXED, __HIP_MEMORY_SCOPE_AGENT);
        if (bb) qb = __hip_atomic_load(hp+1, __ATOMIC_RELAXED, __HIP_MEMORY_SCOPE_AGENT);
        gd++;
      }
      unsigned a0=(unsigned)qa, a1=(unsigned)(qa>>32), a2=(unsigned)qb, a3=(unsigned)(qb>>32);
      pk.x = (a1 & 0xffff0000u) | (a0 >> 16);
      pk.y = (a3 & 0xffff0000u) | (a2 >> 16);
    }
    const int p = t & 1;
    *(uint2*)&h_lds[p][2*tid] = pk;
    __syncthreads();

    float acc[4] = {0.f,0.f,0.f,0.f};
    #pragma unroll
    for (int kc=0;kc<4;kc++){
      uint4 hw = *(const uint4*)&h_lds[p][4*lane + 256*kc];
      float hf[8];
      hf[0]=bf_lo(hw.x); hf[1]=bf_hi(hw.x); hf[2]=bf_lo(hw.y); hf[3]=bf_hi(hw.y);
      hf[4]=bf_lo(hw.z); hf[5]=bf_hi(hw.z); hf[6]=bf_lo(hw.w); hf[7]=bf_hi(hw.w);
      #pragma unroll
      for (int r=0;r<4;r++)
        #pragma unroll
        for (int j=0;j<8;j++)
          acc[r] = fmaf(wreg[r][kc*8+j], hf[j], acc[r]);
    }

    const int b0 = lane & 1;
    const int b1 = lane & 2;
    float x01 = b0 ? acc[1] : acc[0];
    float y01 = b0 ? acc[0] : acc[1];
    x01 += __shfl_xor(y01, 1);
    float x23 = b0 ? acc[3] : acc[2];
    float y23 = b0 ? acc[2] : acc[3];
    x23 += __shfl_xor(y23, 1);
    float xk = b1 ? x23 : x01;
    float yk = b1 ? x01 : x23;
    xk += __shfl_xor(yk, 2);
    xk += __shfl_xor(xk, 4);
    xk += __shfl_xor(xk, 8);
    xk += __shfl_xor(xk, 16);
    xk += __shfl_xor(xk, 32);

    float pre = xk + __shfl(xp, lane & 3);
    const bool ist = ((lane & 3) == 2);
    float px = ist ? fminf(15.0f, fmaxf(-15.0f, pre)) : pre;
    float e  = __expf(ist ? -2.0f*px : -px);
    float d  = 1.0f/(1.0f + e);
    float gv = ist ? (1.0f - e)*d : d;

    float f  = __shfl(gv, 0);
    float ii = __shfl(gv, 1);
    float cg = __shfl(gv, 2);
    float o  = __shfl(gv, 3);

    c = fmaf(f, c, ii*cg);
    float cx = fminf(15.0f, fmaxf(-15.0f, c));
    float e2 = __expf(-2.0f*cx);
    float h  = o * (1.0f - e2)/(1.0f + e2);

    if (lane == 0)
      __hip_atomic_store(hist + (size_t)t*HID + u, h,
                         __ATOMIC_RELAXED, __HIP_MEMORY_SCOPE_AGENT);
  }
}

// ---------------- Phase C: y[t][o] = W_y[o] @ h_t + b_y[o] ----------------
__global__ __launch_bounds__(256)
void ygemm(const float* __restrict__ hist, const float* __restrict__ Wy,
           const float* __restrict__ by, float* __restrict__ yout)
{
  __shared__ float As[16][68];
  __shared__ float Bs[16][68];
  const int o0 = blockIdx.x * 64;
  const int t0 = blockIdx.y * 64;
  const int tid = threadIdx.x;
  const int tx = tid & 15, ty = tid >> 4;
  const int lr = tid >> 2;
  const int lk = (tid & 3) * 4;
  float acc[4][4] = {};
  for (int k0 = 0; k0 < HID; k0 += 16){
    float4 av = *(const float4*)(hist + (size_t)(t0+lr)*HID + k0 + lk);
    float4 bv = *(const float4*)(Wy   + (size_t)(o0+lr)*HID + k0 + lk);
    __syncthreads();
    As[lk+0][lr]=av.x; As[lk+1][lr]=av.y; As[lk+2][lr]=av.z; As[lk+3][lr]=av.w;
    Bs[lk+0][lr]=bv.x; Bs[lk+1][lr]=bv.y; Bs[lk+2][lr]=bv.z; Bs[lk+3][lr]=bv.w;
    __syncthreads();
    #pragma unroll
    for (int kk=0;kk<16;kk++){
      float a[4], bb[4];
      #pragma unroll
      for (int i=0;i<4;i++) a[i]  = As[kk][ty*4+i];
      #pragma unroll
      for (int j=0;j<4;j++) bb[j] = Bs[kk][tx*4+j];
      #pragma unroll
      for (int i=0;i<4;i++)
        #pragma unroll
        for (int j=0;j<4;j++)
          acc[i][j] = fmaf(a[i], bb[j], acc[i][j]);
    }
  }
  #pragma unroll
  for (int i=0;i<4;i++){
    int t = t0 + ty*4 + i;
    #pragma unroll
    for (int jj=0;jj<4;jj++){
      int o = o0 + tx*4 + jj;
      yout[(size_t)t*OUTW + o] = acc[i][jj] + by[o];
    }
  }
}

extern "C" void kernel_launch(void* const* d_in, const int* in_sizes, int n_in,
                              void* d_out, int out_size, void* d_ws, size_t ws_size,
                              hipStream_t stream) {
  const float* X  = (const float*)d_in[0];
  const float* Wf = (const float*)d_in[1];
  const float* bf = (const float*)d_in[2];
  const float* Wi = (const float*)d_in[3];
  const float* bi = (const float*)d_in[4];
  const float* Wc = (const float*)d_in[5];
  const float* bc = (const float*)d_in[6];
  const float* Wo = (const float*)d_in[7];
  const float* bo = (const float*)d_in[8];
  const float* Wy = (const float*)d_in[9];
  const float* by = (const float*)d_in[10];

  float* yout = (float*)d_out;                       // [2048][512]
  float* hist = (float*)d_out + (size_t)SEQ*OUTW;    // [2048][2048]

  const size_t XPROJ_BYTES = (size_t)256*SEQ*32*sizeof(unsigned short); // 33,554,432
  const size_t HX_BYTES    = (size_t)SEQ*HID*sizeof(unsigned short);    //  8,388,608
  if (ws_size < XPROJ_BYTES) return;

  unsigned short* xproj = (unsigned short*)d_ws;

  dim3 gA(32, 128);
  dim3 gY(8, 32);

  if (ws_size >= XPROJ_BYTES + HX_BYTES){
    // primary path: bf16 exchange in ws
    unsigned short* hx = (unsigned short*)((char*)d_ws + XPROJ_BYTES);
    fill_sent<<<HX_BYTES/16/256, 256, 0, stream>>>((uint4*)hx);          // 8 MB
    xproj_gemm<<<gA, 256, 0, stream>>>(Wf,Wi,Wc,Wo, bf,bi,bc,bo, X, xproj);
    lstm_scan<<<256, 512, 0, stream>>>(Wf,Wi,Wc,Wo, xproj, hx, hist);
  } else {
    // fallback: fp32 exchange in hist (round-1 design)
    fill_sent<<<((size_t)SEQ*HID*4)/16/256, 256, 0, stream>>>((uint4*)hist); // 16 MB
    xproj_gemm<<<gA, 256, 0, stream>>>(Wf,Wi,Wc,Wo, bf,bi,bc,bo, X, xproj);
    lstm_persistent_fb<<<256, 512, 0, stream>>>(Wf,Wi,Wc,Wo, xproj, hist);
  }
  ygemm<<<gY, 256, 0, stream>>>(hist, Wy, by, yout);
}